// Round 1
// baseline (697.775 us; speedup 1.0000x reference)
//
#include <hip/hip_runtime.h>

// ---------------------------------------------------------------------------
// Swin Transformer block, MI355X gfx950.
// fp32 I/O (per reference dtypes), bf16 internal compute via MFMA 16x16x32.
// Shapes: B=32 H=W=56 C=192 WS=7 SH=3 NH=6 HD=32 N=49 NW=64 HID=768
// ---------------------------------------------------------------------------

typedef __bf16 bf16_t;
typedef __bf16 bf16x8 __attribute__((ext_vector_type(8)));
typedef float  f32x4  __attribute__((ext_vector_type(4)));

__device__ inline float wred_sum(float v) {
#pragma unroll
  for (int o = 32; o; o >>= 1) v += __shfl_xor(v, o);
  return v;
}

__device__ inline float gelu_tanh(float x) {
  float u = 0.7978845608028654f * (x + 0.044715f * x * x * x);
  float e = __expf(2.f * u);
  float t = 1.f - 2.f / (e + 1.f);   // tanh(u); e->inf => 1, e->0 => -1
  return 0.5f * x * (1.f + t);
}

// ---------------------------------------------------------------------------
// K1: LN1 + roll(-3,-3) + window partition.  One wave per destination token.
// dst row = winLocal*49 + t  (winLocal = bLocal*64 + wi)
// ---------------------------------------------------------------------------
__global__ __launch_bounds__(256) void k_ln1_win(
    const float* __restrict__ x, const float* __restrict__ sc,
    const float* __restrict__ bi, bf16_t* __restrict__ yw, int b0, int nTok) {
  int wv = (int)((blockIdx.x * 256 + threadIdx.x) >> 6);
  int lane = threadIdx.x & 63;
  if (wv >= nTok) return;
  int winL = wv / 49;
  int t = wv - winL * 49;
  int wi = winL & 63;
  int b = b0 + (winL >> 6);
  int t7 = t / 7;
  int hr = (wi >> 3) * 7 + t7;
  int wr = (wi & 7) * 7 + (t - t7 * 7);
  int h = hr + 3; if (h >= 56) h -= 56;   // roll(-3): out[i] = in[i+3 mod 56]
  int w = wr + 3; if (w >= 56) w -= 56;
  const float* xp = x + (((size_t)(b * 56 + h)) * 56 + w) * 192;
  float v0 = xp[lane], v1 = xp[lane + 64], v2 = xp[lane + 128];
  float s = wred_sum(v0 + v1 + v2);
  float q = wred_sum(v0 * v0 + v1 * v1 + v2 * v2);
  float mu = s * (1.f / 192.f);
  float var = q * (1.f / 192.f) - mu * mu;
  float rs = rsqrtf(var + 1e-6f);
  bf16_t* op = yw + (size_t)wv * 192;
  op[lane]       = (bf16_t)((v0 - mu) * rs * sc[lane]       + bi[lane]);
  op[lane + 64]  = (bf16_t)((v1 - mu) * rs * sc[lane + 64]  + bi[lane + 64]);
  op[lane + 128] = (bf16_t)((v2 - mu) * rs * sc[lane + 128] + bi[lane + 128]);
}

// ---------------------------------------------------------------------------
// K2: transpose + fp32->bf16.  out[n*K + k] = in[k*N + n]
// ---------------------------------------------------------------------------
__global__ __launch_bounds__(256) void k_transpose_cvt(
    const float* __restrict__ in, bf16_t* __restrict__ out, int K, int N) {
  int idx = blockIdx.x * 256 + threadIdx.x;
  if (idx >= K * N) return;
  int n = idx / K, k = idx - n * K;
  out[idx] = (bf16_t)in[(size_t)k * N + n];
}

// ---------------------------------------------------------------------------
// K3/K5/K7/K8: MFMA GEMM.  C[M][Nn] = A[M][K] @ Bt[Nn][K]^T + bias
//   block 128x64, 2 waves, wave tile 64x64 (4x4 16x16x32 MFMAs / k-step)
//   mode 0: bf16 out.  1: bf16 out + gelu.  2: fp32 out += (residual accum)
// Requires M%128==0, Nn%64==0, K%32==0 (all call sites satisfy).
// ---------------------------------------------------------------------------
__global__ __launch_bounds__(128) void k_gemm(
    const bf16_t* __restrict__ A, const bf16_t* __restrict__ Bt,
    const float* __restrict__ bias, void* __restrict__ Cout,
    int M, int Nn, int K, int mode) {
  __shared__ uint4 As[512];   // 128 rows x 32 bf16 (4 x 16B chunks/row)
  __shared__ uint4 Bs[256];   // 64 rows x 32 bf16
  int tid = threadIdx.x;
  int lane = tid & 63, wv = tid >> 6;
  int c = lane & 15, g = lane >> 4;
  int bm = blockIdx.x, bn = blockIdx.y;
  f32x4 acc[4][4] = {};
  const bf16_t* Abase = A + (size_t)bm * 128 * K;
  const bf16_t* Bbase = Bt + (size_t)bn * 64 * K;
  for (int k0 = 0; k0 < K; k0 += 32) {
#pragma unroll
    for (int p = 0; p < 4; ++p) {                 // stage A: 512 chunks
      int cid = tid + 128 * p;
      int row = cid >> 2, kg = cid & 3;
      As[row * 4 + (kg ^ ((row >> 1) & 3))] =
          *(const uint4*)(Abase + (size_t)row * K + k0 + kg * 8);
    }
#pragma unroll
    for (int p = 0; p < 2; ++p) {                 // stage Bt: 256 chunks
      int cid = tid + 128 * p;
      int row = cid >> 2, kg = cid & 3;
      Bs[row * 4 + (kg ^ ((row >> 1) & 3))] =
          *(const uint4*)(Bbase + (size_t)row * K + k0 + kg * 8);
    }
    __syncthreads();
    bf16x8 af[4], bfr[4];
#pragma unroll
    for (int i = 0; i < 4; ++i) {
      int ra = wv * 64 + i * 16 + c;
      af[i] = *(const bf16x8*)&As[ra * 4 + (g ^ ((ra >> 1) & 3))];
      int rb = i * 16 + c;
      bfr[i] = *(const bf16x8*)&Bs[rb * 4 + (g ^ ((rb >> 1) & 3))];
    }
#pragma unroll
    for (int i = 0; i < 4; ++i)
#pragma unroll
      for (int j = 0; j < 4; ++j)
        acc[i][j] = __builtin_amdgcn_mfma_f32_16x16x32_bf16(af[i], bfr[j],
                                                            acc[i][j], 0, 0, 0);
    __syncthreads();
  }
  // epilogue: D row = 4*(l>>4)+r (+16i +64wv), col = l&15 (+16j)
#pragma unroll
  for (int j = 0; j < 4; ++j) {
    int col = bn * 64 + j * 16 + c;
    float bv = bias[col];
#pragma unroll
    for (int i = 0; i < 4; ++i) {
#pragma unroll
      for (int r = 0; r < 4; ++r) {
        int row = bm * 128 + wv * 64 + i * 16 + g * 4 + r;
        float v = acc[i][j][r] + bv;
        if (mode == 1) v = gelu_tanh(v);
        if (mode == 2) {
          float* o = (float*)Cout + (size_t)row * Nn + col;
          *o += v;
        } else {
          ((bf16_t*)Cout)[(size_t)row * Nn + col] = (bf16_t)v;
        }
      }
    }
  }
}

// ---------------------------------------------------------------------------
// K4: windowed attention, one wave per (window, head).
// qkv layout per window: [49 tokens][3*192] with q@0, k@192, v@384, head h@h*32.
// S via MFMA (Q/K frags direct from global, 16B/lane), in-register softmax,
// P through 8KB XOR-swizzled LDS, PV via MFMA, deferred 1/sum in epilogue.
// ---------------------------------------------------------------------------
__global__ __launch_bounds__(64) void k_attn(
    const bf16_t* __restrict__ qkv, const int* __restrict__ relidx,
    const float* __restrict__ rpb, const float* __restrict__ mask,
    bf16_t* __restrict__ attn_out) {
  __shared__ char sm[8192];
  int blk = blockIdx.x;
  int wL = blk / 6, h = blk - wL * 6;
  int lane = threadIdx.x;
  int c = lane & 15, g = lane >> 4;

  // combined bias (rpb + shifted-window mask) -> LDS bf16 [49][49]
  {
    const float* mw = mask + (size_t)(wL & 63) * 2401;
    __bf16* bl = (__bf16*)sm;
    for (int idx = lane; idx < 2401; idx += 64)
      bl[idx] = (__bf16)(rpb[relidx[idx] * 6 + h] + mw[idx]);
  }

  const bf16_t* baseq = qkv + (size_t)wL * (49 * 576);

  // S = Q K^T  (K dim = HD = 32 -> one MFMA k-step)
  f32x4 s[4][4] = {};
  bf16x8 qf[4], kf[4];
#pragma unroll
  for (int i = 0; i < 4; ++i) {
    int n = c + 16 * i; if (n > 48) n = 48;
    qf[i] = *(const bf16x8*)(baseq + (size_t)n * 576 + h * 32 + g * 8);
  }
#pragma unroll
  for (int j = 0; j < 4; ++j) {
    int m = c + 16 * j; if (m > 48) m = 48;
    kf[j] = *(const bf16x8*)(baseq + (size_t)m * 576 + 192 + h * 32 + g * 8);
  }
#pragma unroll
  for (int i = 0; i < 4; ++i)
#pragma unroll
    for (int j = 0; j < 4; ++j)
      s[i][j] = __builtin_amdgcn_mfma_f32_16x16x32_bf16(qf[i], kf[j], s[i][j],
                                                        0, 0, 0);

  // scale + bias, mask cols >= 49; row max
  const __bf16* bl = (const __bf16*)sm;
  float mxv[4][4], sum[4][4];
#pragma unroll
  for (int i = 0; i < 4; ++i)
#pragma unroll
    for (int r = 0; r < 4; ++r) {
      int n = 16 * i + 4 * g + r;
      int nc = n > 48 ? 48 : n;
      float best = -1e30f;
#pragma unroll
      for (int j = 0; j < 4; ++j) {
        int m = 16 * j + c;
        float v = -1e30f;
        if (m < 49)
          v = s[i][j][r] * 0.17677669529663687f + (float)bl[nc * 49 + m];
        s[i][j][r] = v;
        best = fmaxf(best, v);
      }
      mxv[i][r] = best;
    }
#pragma unroll
  for (int o = 8; o; o >>= 1)
#pragma unroll
    for (int i = 0; i < 4; ++i)
#pragma unroll
      for (int r = 0; r < 4; ++r)
        mxv[i][r] = fmaxf(mxv[i][r], __shfl_xor(mxv[i][r], o));
  // exp + row sum (unnormalized P; exp(-1e30 - mx) == 0 kills masked cols)
#pragma unroll
  for (int i = 0; i < 4; ++i)
#pragma unroll
    for (int r = 0; r < 4; ++r) {
      float ss = 0.f;
#pragma unroll
      for (int j = 0; j < 4; ++j) {
        float p = __expf(s[i][j][r] - mxv[i][r]);
        s[i][j][r] = p;
        ss += p;
      }
      sum[i][r] = ss;
    }
#pragma unroll
  for (int o = 8; o; o >>= 1)
#pragma unroll
    for (int i = 0; i < 4; ++i)
#pragma unroll
      for (int r = 0; r < 4; ++r)
        sum[i][r] += __shfl_xor(sum[i][r], o);

  // write P (bf16) into swizzled LDS [64 rows][128B], overwriting bias
#pragma unroll
  for (int i = 0; i < 4; ++i)
#pragma unroll
    for (int j = 0; j < 4; ++j)
#pragma unroll
      for (int r = 0; r < 4; ++r) {
        int n = 16 * i + 4 * g + r;
        int m = 16 * j + c;
        int offb = n * 128 + ((2 * m) ^ ((n & 7) << 4));
        *(__bf16*)(sm + offb) = (__bf16)s[i][j][r];
      }

  // O = P V
  f32x4 o2[4][2] = {};
#pragma unroll
  for (int kt = 0; kt < 2; ++kt) {
    bf16x8 pf[4], vf[2];
#pragma unroll
    for (int i = 0; i < 4; ++i) {
      int n = c + 16 * i;
      int cb = (16 * g + 64 * kt) ^ ((n & 7) << 4);
      pf[i] = *(const bf16x8*)(sm + n * 128 + cb);
    }
#pragma unroll
    for (int dt = 0; dt < 2; ++dt) {
      int d = c + 16 * dt;
      union { bf16x8 v; __bf16 e[8]; } u;
#pragma unroll
      for (int e0 = 0; e0 < 8; ++e0) {
        int m = 8 * g + e0 + 32 * kt; if (m > 48) m = 48;  // P col is 0 there
        u.e[e0] = baseq[(size_t)m * 576 + 384 + h * 32 + d];
      }
      vf[dt] = u.v;
    }
#pragma unroll
    for (int i = 0; i < 4; ++i)
#pragma unroll
      for (int dt = 0; dt < 2; ++dt)
        o2[i][dt] = __builtin_amdgcn_mfma_f32_16x16x32_bf16(pf[i], vf[dt],
                                                            o2[i][dt], 0, 0, 0);
  }

  // epilogue with deferred softmax normalization (sum stays lane-local)
#pragma unroll
  for (int i = 0; i < 4; ++i)
#pragma unroll
    for (int dt = 0; dt < 2; ++dt)
#pragma unroll
      for (int r = 0; r < 4; ++r) {
        int n = 16 * i + 4 * g + r;
        if (n < 49) {
          int d = 16 * dt + c;
          attn_out[((size_t)wL * 49 + n) * 192 + h * 32 + d] =
              (bf16_t)(o2[i][dt][r] / sum[i][r]);
        }
      }
}

// ---------------------------------------------------------------------------
// K6: window reverse + un-shift + residual (fp32 -> d_out) + LN2 -> z (bf16)
// ---------------------------------------------------------------------------
__global__ __launch_bounds__(256) void k_unwin_ln2(
    const float* __restrict__ x, const bf16_t* __restrict__ projw,
    const float* __restrict__ sc, const float* __restrict__ bi,
    float* __restrict__ out, bf16_t* __restrict__ z, int b0, int nTok) {
  int wv = (int)((blockIdx.x * 256 + threadIdx.x) >> 6);
  int lane = threadIdx.x & 63;
  if (wv >= nTok) return;
  int bL = wv / 3136;
  int rem = wv - bL * 3136;
  int hh = rem / 56, ww2 = rem - hh * 56;
  int b = b0 + bL;
  int hr = hh + 53; if (hr >= 56) hr -= 56;   // roll(+3): in[(i-3) mod 56]
  int wr = ww2 + 53; if (wr >= 56) wr -= 56;
  int winL = bL * 64 + (hr / 7) * 8 + (wr / 7);
  int t = (hr % 7) * 7 + (wr % 7);
  const bf16_t* pp = projw + ((size_t)winL * 49 + t) * 192;
  size_t gtok = ((size_t)(b * 56 + hh)) * 56 + ww2;
  const float* xp = x + gtok * 192;
  float v0 = xp[lane]       + (float)pp[lane];
  float v1 = xp[lane + 64]  + (float)pp[lane + 64];
  float v2 = xp[lane + 128] + (float)pp[lane + 128];
  float* op = out + gtok * 192;
  op[lane] = v0; op[lane + 64] = v1; op[lane + 128] = v2;
  float s = wred_sum(v0 + v1 + v2);
  float q = wred_sum(v0 * v0 + v1 * v1 + v2 * v2);
  float mu = s * (1.f / 192.f);
  float var = q * (1.f / 192.f) - mu * mu;
  float rs = rsqrtf(var + 1e-6f);
  bf16_t* zp = z + gtok * 192;
  zp[lane]       = (bf16_t)((v0 - mu) * rs * sc[lane]       + bi[lane]);
  zp[lane + 64]  = (bf16_t)((v1 - mu) * rs * sc[lane + 64]  + bi[lane + 64]);
  zp[lane + 128] = (bf16_t)((v2 - mu) * rs * sc[lane + 128] + bi[lane + 128]);
}

// ---------------------------------------------------------------------------
extern "C" void kernel_launch(void* const* d_in, const int* in_sizes, int n_in,
                              void* d_out, int out_size, void* d_ws,
                              size_t ws_size, hipStream_t stream) {
  (void)in_sizes; (void)n_in; (void)out_size;
  const float* x     = (const float*)d_in[0];
  const float* maskp = (const float*)d_in[1];
  const int*   reli  = (const int*)d_in[2];
  const float* ln1s  = (const float*)d_in[3];
  const float* ln1b  = (const float*)d_in[4];
  const float* qkvw  = (const float*)d_in[5];
  const float* qkvb  = (const float*)d_in[6];
  const float* rpb   = (const float*)d_in[7];
  const float* projw = (const float*)d_in[8];
  const float* projb = (const float*)d_in[9];
  const float* ln2s  = (const float*)d_in[10];
  const float* ln2b  = (const float*)d_in[11];
  const float* w1    = (const float*)d_in[12];
  const float* b1    = (const float*)d_in[13];
  const float* w2    = (const float*)d_in[14];
  const float* b2    = (const float*)d_in[15];
  float* out = (float*)d_out;

  auto aup = [](size_t v) { return (v + 255) & ~(size_t)255; };
  char* base = (char*)d_ws;
  size_t off = 0;
  bf16_t* z_buf = (bf16_t*)(base + off); off += aup((size_t)100352 * 192 * 2);
  bf16_t* qkvT  = (bf16_t*)(base + off); off += aup((size_t)576 * 192 * 2);
  bf16_t* projT = (bf16_t*)(base + off); off += aup((size_t)192 * 192 * 2);
  bf16_t* w1T   = (bf16_t*)(base + off); off += aup((size_t)768 * 192 * 2);
  bf16_t* w2T   = (bf16_t*)(base + off); off += aup((size_t)192 * 768 * 2);
  size_t offB = off;

  // adaptive batch chunk: need Bc*3136*(576+192)*2 bytes past offB
  int Bc = 32;
  while (Bc > 2 && offB + (size_t)Bc * 3136 * (576 + 192) * 2 > ws_size)
    Bc >>= 1;
  bf16_t* bufB = (bf16_t*)(base + offB);
  bf16_t* bufA = (bf16_t*)(base + offB + aup((size_t)Bc * 3136 * 576 * 2));

  // MLP hidden chunk (rows, multiple of 128) fitting in [offB, ws_size)
  size_t hBytes = (ws_size > offB) ? (ws_size - offB) : 0;
  long long HcL = (long long)((hBytes / 1536) & ~(size_t)127);
  int Hc = (int)(HcL > 100352 ? 100352 : HcL);
  if (Hc < 128) Hc = 128;

  // weight transposes (fp32 -> bf16, B^T layout)
  k_transpose_cvt<<<(192 * 576 + 255) / 256, 256, 0, stream>>>(qkvw, qkvT, 192, 576);
  k_transpose_cvt<<<(192 * 192 + 255) / 256, 256, 0, stream>>>(projw, projT, 192, 192);
  k_transpose_cvt<<<(192 * 768 + 255) / 256, 256, 0, stream>>>(w1, w1T, 192, 768);
  k_transpose_cvt<<<(768 * 192 + 255) / 256, 256, 0, stream>>>(w2, w2T, 768, 192);

  for (int b0 = 0; b0 < 32; b0 += Bc) {
    int nTok = Bc * 3136, nWin = Bc * 64;
    k_ln1_win<<<nTok / 4, 256, 0, stream>>>(x, ln1s, ln1b, bufA, b0, nTok);
    k_gemm<<<dim3(nTok / 128, 576 / 64), 128, 0, stream>>>(
        bufA, qkvT, qkvb, (void*)bufB, nTok, 576, 192, 0);
    k_attn<<<nWin * 6, 64, 0, stream>>>(bufB, reli, rpb, maskp, bufA);
    k_gemm<<<dim3(nTok / 128, 192 / 64), 128, 0, stream>>>(
        bufA, projT, projb, (void*)bufB, nTok, 192, 192, 0);
    k_unwin_ln2<<<nTok / 4, 256, 0, stream>>>(x, bufB, ln2s, ln2b, out, z_buf,
                                              b0, nTok);
  }

  for (int r0 = 0; r0 < 100352; r0 += Hc) {
    int rows = 100352 - r0; if (rows > Hc) rows = Hc;
    k_gemm<<<dim3(rows / 128, 768 / 64), 128, 0, stream>>>(
        z_buf + (size_t)r0 * 192, w1T, b1, (void*)bufB, rows, 768, 192, 1);
    k_gemm<<<dim3(rows / 128, 192 / 64), 128, 0, stream>>>(
        bufB, w2T, b2, (void*)(out + (size_t)r0 * 192), rows, 192, 768, 2);
  }
}

// Round 3
// 678.622 us; speedup vs baseline: 1.0282x; 1.0282x over previous
//
#include <hip/hip_runtime.h>

// ---------------------------------------------------------------------------
// Swin Transformer block, MI355X gfx950.  fp32 I/O, bf16 MFMA internals.
// B=32 H=W=56 C=192 WS=7 SH=3 NH=6 HD=32 N=49 NW=64 HID=768
// R1: B-stationary barrier-free GEMM (swapped-operand epilogue) + fused MLP.
// R2: identical resubmit (R1 bench was a container-infra failure, no data).
// ---------------------------------------------------------------------------

typedef __bf16 bf16_t;
typedef __bf16 bf16x8 __attribute__((ext_vector_type(8)));
typedef float  f32x4  __attribute__((ext_vector_type(4)));

__device__ inline float wred_sum(float v) {
#pragma unroll
  for (int o = 32; o; o >>= 1) v += __shfl_xor(v, o);
  return v;
}

__device__ inline float gelu_tanh(float x) {
  float u = 0.7978845608028654f * (x + 0.044715f * x * x * x);
  float e = __expf(2.f * u);
  float t = 1.f - 2.f / (e + 1.f);   // tanh(u)
  return 0.5f * x * (1.f + t);
}

// ---------------------------------------------------------------------------
// K1: LN1 + roll(-3,-3) + window partition.  One wave per destination token.
// ---------------------------------------------------------------------------
__global__ __launch_bounds__(256) void k_ln1_win(
    const float* __restrict__ x, const float* __restrict__ sc,
    const float* __restrict__ bi, bf16_t* __restrict__ yw, int b0, int nTok) {
  int wv = (int)((blockIdx.x * 256 + threadIdx.x) >> 6);
  int lane = threadIdx.x & 63;
  if (wv >= nTok) return;
  int winL = wv / 49;
  int t = wv - winL * 49;
  int wi = winL & 63;
  int b = b0 + (winL >> 6);
  int t7 = t / 7;
  int hr = (wi >> 3) * 7 + t7;
  int wr = (wi & 7) * 7 + (t - t7 * 7);
  int h = hr + 3; if (h >= 56) h -= 56;
  int w = wr + 3; if (w >= 56) w -= 56;
  const float* xp = x + (((size_t)(b * 56 + h)) * 56 + w) * 192;
  float v0 = xp[lane], v1 = xp[lane + 64], v2 = xp[lane + 128];
  float s = wred_sum(v0 + v1 + v2);
  float q = wred_sum(v0 * v0 + v1 * v1 + v2 * v2);
  float mu = s * (1.f / 192.f);
  float var = q * (1.f / 192.f) - mu * mu;
  float rs = rsqrtf(var + 1e-6f);
  bf16_t* op = yw + (size_t)wv * 192;
  op[lane]       = (bf16_t)((v0 - mu) * rs * sc[lane]       + bi[lane]);
  op[lane + 64]  = (bf16_t)((v1 - mu) * rs * sc[lane + 64]  + bi[lane + 64]);
  op[lane + 128] = (bf16_t)((v2 - mu) * rs * sc[lane + 128] + bi[lane + 128]);
}

// ---------------------------------------------------------------------------
// K2: transpose + fp32->bf16.  out[n*K + k] = in[k*N + n]
// ---------------------------------------------------------------------------
__global__ __launch_bounds__(256) void k_transpose_cvt(
    const float* __restrict__ in, bf16_t* __restrict__ out, int K, int N) {
  int idx = blockIdx.x * 256 + threadIdx.x;
  if (idx >= K * N) return;
  int n = idx / K, k = idx - n * K;
  out[idx] = (bf16_t)in[(size_t)k * N + n];
}

// ---------------------------------------------------------------------------
// K3: B-stationary GEMM, zero barriers.  C[M][Nn] = A[M][K] @ Bt[Nn][K]^T + b
// Block = 4 waves stacked over rows (tile 256xK -> 64-col stripe bn).
// B frags hoisted to VGPR once per block; A frags 16B/lane direct from global.
// Swapped MFMA operands: lane holds 4 consecutive out cols -> 8B bf16 stores.
// Requires M%256==0, Nn%64==0, K%32==0.
// ---------------------------------------------------------------------------
template <int K>
__global__ __launch_bounds__(256, 2) void k_gemm_bs(
    const bf16_t* __restrict__ A, const bf16_t* __restrict__ Bt,
    const float* __restrict__ bias, bf16_t* __restrict__ C, int Nn, int nMt) {
  constexpr int NKS = K / 32;
  int tid = threadIdx.x;
  int w = tid >> 6, lane = tid & 63;
  int c = lane & 15, g = lane >> 4;
  int bn = blockIdx.x;
  bf16x8 bf[4][NKS];
  const bf16_t* bp = Bt + (size_t)(bn * 64 + c) * K + 8 * g;
#pragma unroll
  for (int jc = 0; jc < 4; ++jc)
#pragma unroll
    for (int ks = 0; ks < NKS; ++ks)
      bf[jc][ks] = *(const bf16x8*)(bp + (size_t)jc * 16 * K + 32 * ks);
  float4 bias4[4];
#pragma unroll
  for (int jc = 0; jc < 4; ++jc)
    bias4[jc] = *(const float4*)(bias + bn * 64 + jc * 16 + 4 * g);
  for (int mt = blockIdx.y; mt < nMt; mt += gridDim.y) {
    int m0 = mt * 256 + w * 64;
    f32x4 acc[4][4] = {};  // [jc][ir]
    const bf16_t* ap = A + (size_t)(m0 + c) * K + 8 * g;
#pragma unroll
    for (int ks = 0; ks < NKS; ++ks) {
      bf16x8 af[4];
#pragma unroll
      for (int ir = 0; ir < 4; ++ir)
        af[ir] = *(const bf16x8*)(ap + (size_t)ir * 16 * K + 32 * ks);
#pragma unroll
      for (int jc = 0; jc < 4; ++jc)
#pragma unroll
        for (int ir = 0; ir < 4; ++ir)
          acc[jc][ir] = __builtin_amdgcn_mfma_f32_16x16x32_bf16(
              bf[jc][ks], af[ir], acc[jc][ir], 0, 0, 0);
    }
    // lane: out[row = m0 + ir*16 + c][col = bn*64 + jc*16 + 4g + r], r=0..3
#pragma unroll
    for (int ir = 0; ir < 4; ++ir) {
      bf16_t* cp = C + (size_t)(m0 + ir * 16 + c) * Nn + bn * 64 + 4 * g;
#pragma unroll
      for (int jc = 0; jc < 4; ++jc) {
        union { uint2 u; bf16_t e[4]; } pk;
#pragma unroll
        for (int r = 0; r < 4; ++r)
          pk.e[r] = (bf16_t)(acc[jc][ir][r] + ((const float*)&bias4[jc])[r]);
        *(uint2*)(cp + jc * 16) = pk.u;
      }
    }
  }
}

// ---------------------------------------------------------------------------
// K4: windowed attention, one wave per (window, head).
// ---------------------------------------------------------------------------
__global__ __launch_bounds__(64) void k_attn(
    const bf16_t* __restrict__ qkv, const int* __restrict__ relidx,
    const float* __restrict__ rpb, const float* __restrict__ mask,
    bf16_t* __restrict__ attn_out) {
  __shared__ char sm[8192];
  int blk = blockIdx.x;
  int wL = blk / 6, h = blk - wL * 6;
  int lane = threadIdx.x;
  int c = lane & 15, g = lane >> 4;
  {
    const float* mw = mask + (size_t)(wL & 63) * 2401;
    __bf16* bl = (__bf16*)sm;
    for (int idx = lane; idx < 2401; idx += 64)
      bl[idx] = (__bf16)(rpb[relidx[idx] * 6 + h] + mw[idx]);
  }
  const bf16_t* baseq = qkv + (size_t)wL * (49 * 576);
  f32x4 s[4][4] = {};
  bf16x8 qf[4], kf[4];
#pragma unroll
  for (int i = 0; i < 4; ++i) {
    int n = c + 16 * i; if (n > 48) n = 48;
    qf[i] = *(const bf16x8*)(baseq + (size_t)n * 576 + h * 32 + g * 8);
  }
#pragma unroll
  for (int j = 0; j < 4; ++j) {
    int m = c + 16 * j; if (m > 48) m = 48;
    kf[j] = *(const bf16x8*)(baseq + (size_t)m * 576 + 192 + h * 32 + g * 8);
  }
#pragma unroll
  for (int i = 0; i < 4; ++i)
#pragma unroll
    for (int j = 0; j < 4; ++j)
      s[i][j] = __builtin_amdgcn_mfma_f32_16x16x32_bf16(qf[i], kf[j], s[i][j],
                                                        0, 0, 0);
  const __bf16* bl = (const __bf16*)sm;
  float mxv[4][4], sum[4][4];
#pragma unroll
  for (int i = 0; i < 4; ++i)
#pragma unroll
    for (int r = 0; r < 4; ++r) {
      int n = 16 * i + 4 * g + r;
      int nc = n > 48 ? 48 : n;
      float best = -1e30f;
#pragma unroll
      for (int j = 0; j < 4; ++j) {
        int m = 16 * j + c;
        float v = -1e30f;
        if (m < 49)
          v = s[i][j][r] * 0.17677669529663687f + (float)bl[nc * 49 + m];
        s[i][j][r] = v;
        best = fmaxf(best, v);
      }
      mxv[i][r] = best;
    }
#pragma unroll
  for (int o = 8; o; o >>= 1)
#pragma unroll
    for (int i = 0; i < 4; ++i)
#pragma unroll
      for (int r = 0; r < 4; ++r)
        mxv[i][r] = fmaxf(mxv[i][r], __shfl_xor(mxv[i][r], o));
#pragma unroll
  for (int i = 0; i < 4; ++i)
#pragma unroll
    for (int r = 0; r < 4; ++r) {
      float ss = 0.f;
#pragma unroll
      for (int j = 0; j < 4; ++j) {
        float p = __expf(s[i][j][r] - mxv[i][r]);
        s[i][j][r] = p;
        ss += p;
      }
      sum[i][r] = ss;
    }
#pragma unroll
  for (int o = 8; o; o >>= 1)
#pragma unroll
    for (int i = 0; i < 4; ++i)
#pragma unroll
      for (int r = 0; r < 4; ++r)
        sum[i][r] += __shfl_xor(sum[i][r], o);
#pragma unroll
  for (int i = 0; i < 4; ++i)
#pragma unroll
    for (int j = 0; j < 4; ++j)
#pragma unroll
      for (int r = 0; r < 4; ++r) {
        int n = 16 * i + 4 * g + r;
        int m = 16 * j + c;
        int offb = n * 128 + ((2 * m) ^ ((n & 7) << 4));
        *(__bf16*)(sm + offb) = (__bf16)s[i][j][r];
      }
  f32x4 o2[4][2] = {};
#pragma unroll
  for (int kt = 0; kt < 2; ++kt) {
    bf16x8 pf[4], vf[2];
#pragma unroll
    for (int i = 0; i < 4; ++i) {
      int n = c + 16 * i;
      int cb = (16 * g + 64 * kt) ^ ((n & 7) << 4);
      pf[i] = *(const bf16x8*)(sm + n * 128 + cb);
    }
#pragma unroll
    for (int dt = 0; dt < 2; ++dt) {
      int d = c + 16 * dt;
      union { bf16x8 v; __bf16 e[8]; } u;
#pragma unroll
      for (int e0 = 0; e0 < 8; ++e0) {
        int m = 8 * g + e0 + 32 * kt; if (m > 48) m = 48;
        u.e[e0] = baseq[(size_t)m * 576 + 384 + h * 32 + d];
      }
      vf[dt] = u.v;
    }
#pragma unroll
    for (int i = 0; i < 4; ++i)
#pragma unroll
      for (int dt = 0; dt < 2; ++dt)
        o2[i][dt] = __builtin_amdgcn_mfma_f32_16x16x32_bf16(pf[i], vf[dt],
                                                            o2[i][dt], 0, 0, 0);
  }
#pragma unroll
  for (int i = 0; i < 4; ++i)
#pragma unroll
    for (int dt = 0; dt < 2; ++dt)
#pragma unroll
      for (int r = 0; r < 4; ++r) {
        int n = 16 * i + 4 * g + r;
        if (n < 49) {
          int d = 16 * dt + c;
          attn_out[((size_t)wL * 49 + n) * 192 + h * 32 + d] =
              (bf16_t)(o2[i][dt][r] / sum[i][r]);
        }
      }
}

// ---------------------------------------------------------------------------
// K6: window reverse + un-shift + residual -> d_out + LN2 -> z (bf16)
// ---------------------------------------------------------------------------
__global__ __launch_bounds__(256) void k_unwin_ln2(
    const float* __restrict__ x, const bf16_t* __restrict__ projw,
    const float* __restrict__ sc, const float* __restrict__ bi,
    float* __restrict__ out, bf16_t* __restrict__ z, int b0, int nTok) {
  int wv = (int)((blockIdx.x * 256 + threadIdx.x) >> 6);
  int lane = threadIdx.x & 63;
  if (wv >= nTok) return;
  int bL = wv / 3136;
  int rem = wv - bL * 3136;
  int hh = rem / 56, ww2 = rem - hh * 56;
  int b = b0 + bL;
  int hr = hh + 53; if (hr >= 56) hr -= 56;
  int wr = ww2 + 53; if (wr >= 56) wr -= 56;
  int winL = bL * 64 + (hr / 7) * 8 + (wr / 7);
  int t = (hr % 7) * 7 + (wr % 7);
  const bf16_t* pp = projw + ((size_t)winL * 49 + t) * 192;
  size_t gtok = ((size_t)(b * 56 + hh)) * 56 + ww2;
  const float* xp = x + gtok * 192;
  float v0 = xp[lane]       + (float)pp[lane];
  float v1 = xp[lane + 64]  + (float)pp[lane + 64];
  float v2 = xp[lane + 128] + (float)pp[lane + 128];
  float* op = out + gtok * 192;
  op[lane] = v0; op[lane + 64] = v1; op[lane + 128] = v2;
  float s = wred_sum(v0 + v1 + v2);
  float q = wred_sum(v0 * v0 + v1 * v1 + v2 * v2);
  float mu = s * (1.f / 192.f);
  float var = q * (1.f / 192.f) - mu * mu;
  float rs = rsqrtf(var + 1e-6f);
  bf16_t* zp = z + gtok * 192;
  zp[lane]       = (bf16_t)((v0 - mu) * rs * sc[lane]       + bi[lane]);
  zp[lane + 64]  = (bf16_t)((v1 - mu) * rs * sc[lane + 64]  + bi[lane + 64]);
  zp[lane + 128] = (bf16_t)((v2 - mu) * rs * sc[lane + 128] + bi[lane + 128]);
}

// ---------------------------------------------------------------------------
// K7: fused MLP.  out[m][192] += gelu(z[m][192] @ w1 + b1) @ w2 + b2
// Block = 4 waves (2x2), m-tile 128 rows, hidden in 6 chunks of 128 via
// 32KB XOR-swizzled LDS.  acc2 (out, fp32) persists across chunks.
// ---------------------------------------------------------------------------
__global__ __launch_bounds__(256, 2) void k_mlp_fused(
    const bf16_t* __restrict__ z, const bf16_t* __restrict__ w1T,
    const float* __restrict__ b1, const bf16_t* __restrict__ w2T,
    const float* __restrict__ b2, float* __restrict__ out) {
  __shared__ char hsm[128 * 256];  // h chunk [128 rows][128 cols bf16], swizzled
  int tid = threadIdx.x;
  int w = tid >> 6, lane = tid & 63;
  int c = lane & 15, g = lane >> 4;
  int wr = w >> 1, wc = w & 1;
  int m0 = blockIdx.x * 128;
  f32x4 acc2[6][4] = {};  // [jc][ir]: col = wc*96+jc*16+4g+r, row = wr*64+ir*16+c
  for (int hc = 0; hc < 6; ++hc) {
    // ---- gemm1: h_chunk = z @ w1T^T  (wave: rows wr*64.., hcols wc*64..)
    f32x4 acc1[4][4] = {};  // [jh][ir]
    const bf16_t* zp = z + (size_t)(m0 + wr * 64 + c) * 192 + 8 * g;
    const bf16_t* w1p = w1T + (size_t)(hc * 128 + wc * 64 + c) * 192 + 8 * g;
#pragma unroll
    for (int ks = 0; ks < 6; ++ks) {
      bf16x8 zf[4], wf[4];
#pragma unroll
      for (int i = 0; i < 4; ++i) {
        zf[i] = *(const bf16x8*)(zp + (size_t)i * 16 * 192 + 32 * ks);
        wf[i] = *(const bf16x8*)(w1p + (size_t)i * 16 * 192 + 32 * ks);
      }
#pragma unroll
      for (int jh = 0; jh < 4; ++jh)
#pragma unroll
        for (int ir = 0; ir < 4; ++ir)
          acc1[jh][ir] = __builtin_amdgcn_mfma_f32_16x16x32_bf16(
              wf[jh], zf[ir], acc1[jh][ir], 0, 0, 0);
    }
    if (hc) __syncthreads();  // prev chunk's LDS reads complete
    // ---- bias + gelu + pack 4 cols -> swizzled LDS
#pragma unroll
    for (int jh = 0; jh < 4; ++jh) {
      float4 b1v = *(const float4*)(b1 + hc * 128 + wc * 64 + jh * 16 + 4 * g);
#pragma unroll
      for (int ir = 0; ir < 4; ++ir) {
        union { uint2 u; __bf16 e[4]; } pk;
#pragma unroll
        for (int r = 0; r < 4; ++r)
          pk.e[r] = (__bf16)gelu_tanh(acc1[jh][ir][r] + ((const float*)&b1v)[r]);
        int row = wr * 64 + ir * 16 + c;
        int byo = (wc * 64 + jh * 16 + 4 * g) * 2;
        *(uint2*)(hsm + row * 256 + (byo ^ ((row & 7) << 4))) = pk.u;
      }
    }
    __syncthreads();
    // ---- gemm2: acc2 += h_chunk @ w2T^T   (k = hc*128..+128)
    const bf16_t* w2p = w2T + (size_t)(wc * 96 + c) * 768 + hc * 128 + 8 * g;
#pragma unroll
    for (int ks = 0; ks < 4; ++ks) {
      bf16x8 hf[4], wf2[6];
#pragma unroll
      for (int ir = 0; ir < 4; ++ir) {
        int row = wr * 64 + ir * 16 + c;
        int byo = 16 * g + 64 * ks;
        hf[ir] = *(const bf16x8*)(hsm + row * 256 + (byo ^ ((row & 7) << 4)));
      }
#pragma unroll
      for (int jc = 0; jc < 6; ++jc)
        wf2[jc] = *(const bf16x8*)(w2p + (size_t)jc * 16 * 768 + 32 * ks);
#pragma unroll
      for (int jc = 0; jc < 6; ++jc)
#pragma unroll
        for (int ir = 0; ir < 4; ++ir)
          acc2[jc][ir] = __builtin_amdgcn_mfma_f32_16x16x32_bf16(
              wf2[jc], hf[ir], acc2[jc][ir], 0, 0, 0);
    }
  }
  // ---- epilogue: float4 read-modify-write + b2
#pragma unroll
  for (int jc = 0; jc < 6; ++jc) {
    float4 b2v = *(const float4*)(b2 + wc * 96 + jc * 16 + 4 * g);
#pragma unroll
    for (int ir = 0; ir < 4; ++ir) {
      int row = m0 + wr * 64 + ir * 16 + c;
      float* op = out + (size_t)row * 192 + wc * 96 + jc * 16 + 4 * g;
      float4 cur = *(float4*)op;
      cur.x += acc2[jc][ir][0] + b2v.x;
      cur.y += acc2[jc][ir][1] + b2v.y;
      cur.z += acc2[jc][ir][2] + b2v.z;
      cur.w += acc2[jc][ir][3] + b2v.w;
      *(float4*)op = cur;
    }
  }
}

// ---------------------------------------------------------------------------
extern "C" void kernel_launch(void* const* d_in, const int* in_sizes, int n_in,
                              void* d_out, int out_size, void* d_ws,
                              size_t ws_size, hipStream_t stream) {
  (void)in_sizes; (void)n_in; (void)out_size;
  const float* x     = (const float*)d_in[0];
  const float* maskp = (const float*)d_in[1];
  const int*   reli  = (const int*)d_in[2];
  const float* ln1s  = (const float*)d_in[3];
  const float* ln1b  = (const float*)d_in[4];
  const float* qkvw  = (const float*)d_in[5];
  const float* qkvb  = (const float*)d_in[6];
  const float* rpb   = (const float*)d_in[7];
  const float* projw = (const float*)d_in[8];
  const float* projb = (const float*)d_in[9];
  const float* ln2s  = (const float*)d_in[10];
  const float* ln2b  = (const float*)d_in[11];
  const float* w1    = (const float*)d_in[12];
  const float* b1    = (const float*)d_in[13];
  const float* w2    = (const float*)d_in[14];
  const float* b2    = (const float*)d_in[15];
  float* out = (float*)d_out;

  auto aup = [](size_t v) { return (v + 255) & ~(size_t)255; };
  char* base = (char*)d_ws;
  size_t off = 0;
  bf16_t* z_buf = (bf16_t*)(base + off); off += aup((size_t)100352 * 192 * 2);
  bf16_t* qkvT  = (bf16_t*)(base + off); off += aup((size_t)576 * 192 * 2);
  bf16_t* projT = (bf16_t*)(base + off); off += aup((size_t)192 * 192 * 2);
  bf16_t* w1T   = (bf16_t*)(base + off); off += aup((size_t)768 * 192 * 2);
  bf16_t* w2T   = (bf16_t*)(base + off); off += aup((size_t)192 * 768 * 2);
  size_t offB = off;

  int Bc = 32;  // batch chunk (multiple of 4 keeps M%256==0)
  while (Bc > 4 && offB + (size_t)Bc * 3136 * (576 + 192) * 2 > ws_size)
    Bc >>= 1;
  bf16_t* bufB = (bf16_t*)(base + offB);
  bf16_t* bufA = (bf16_t*)(base + offB + aup((size_t)Bc * 3136 * 576 * 2));

  k_transpose_cvt<<<(192 * 576 + 255) / 256, 256, 0, stream>>>(qkvw, qkvT, 192, 576);
  k_transpose_cvt<<<(192 * 192 + 255) / 256, 256, 0, stream>>>(projw, projT, 192, 192);
  k_transpose_cvt<<<(192 * 768 + 255) / 256, 256, 0, stream>>>(w1, w1T, 192, 768);
  k_transpose_cvt<<<(768 * 192 + 255) / 256, 256, 0, stream>>>(w2, w2T, 768, 192);

  for (int b0 = 0; b0 < 32; b0 += Bc) {
    int nTok = Bc * 3136, nWin = Bc * 64;
    int nMt = nTok / 256;
    k_ln1_win<<<nTok / 4, 256, 0, stream>>>(x, ln1s, ln1b, bufA, b0, nTok);
    {
      int nbn = 576 / 64;
      int gy = (512 + nbn - 1) / nbn; if (gy > nMt) gy = nMt;
      k_gemm_bs<192><<<dim3(nbn, gy), 256, 0, stream>>>(bufA, qkvT, qkvb, bufB,
                                                        576, nMt);
    }
    k_attn<<<nWin * 6, 64, 0, stream>>>(bufB, reli, rpb, maskp, bufA);
    {
      int nbn = 192 / 64;
      int gy = (512 + nbn - 1) / nbn; if (gy > nMt) gy = nMt;
      k_gemm_bs<192><<<dim3(nbn, gy), 256, 0, stream>>>(bufA, projT, projb,
                                                        bufB, 192, nMt);
    }
    k_unwin_ln2<<<nTok / 4, 256, 0, stream>>>(x, bufB, ln2s, ln2b, out, z_buf,
                                              b0, nTok);
  }

  k_mlp_fused<<<100352 / 128, 256, 0, stream>>>(z_buf, w1T, b1, w2T, b2, out);
}